// Round 2
// baseline (381.850 us; speedup 1.0000x reference)
//
#include <hip/hip_runtime.h>
#include <hip/hip_bf16.h>

typedef __attribute__((ext_vector_type(8))) short bf16x8;
typedef __attribute__((ext_vector_type(4))) float f32x4;

// fp32 -> bf16 round-to-nearest-even (bit twiddle; inputs are finite randoms)
__device__ __forceinline__ short f2bf(float f) {
    union { float f; unsigned u; } v; v.f = f;
    unsigned u = v.u;
    return (short)((u + 0x7FFFu + ((u >> 16) & 1u)) >> 16);
}

// Grid map (256 rows per block, rows_l = 20000*(2l+1), all multiples of 16):
// blocks per l: 79,235,391,547,704,860 ; cumulative: 0,79,314,705,1252,1956,2816
__global__ void __launch_bounds__(256) combine_mfma_kernel(
    const float* __restrict__ A0, const float* __restrict__ A1,
    const float* __restrict__ A2, const float* __restrict__ A3,
    const float* __restrict__ A4, const float* __restrict__ A5,
    const float* __restrict__ W, float* __restrict__ out)
{
    int b = (int)blockIdx.x;
    int l, boff;
    if      (b <   79) { l = 0; boff = 0;    }
    else if (b <  314) { l = 1; boff = 79;   }
    else if (b <  705) { l = 2; boff = 314;  }
    else if (b < 1252) { l = 3; boff = 705;  }
    else if (b < 1956) { l = 4; boff = 1252; }
    else               { l = 5; boff = 1956; }
    const float* A = (l==0)?A0:(l==1)?A1:(l==2)?A2:(l==3)?A3:(l==4)?A4:A5;
    const int rows = 20000 * (2*l + 1);
    const int row_start = (b - boff) * 256;
    const int ntiles = min(256, rows - row_start) >> 4;   // 16-row MFMA tiles
    const size_t outbase = (size_t)20000 * l * l;         // sum of odd numbers = l^2

    const int lane = (int)threadIdx.x & 63;
    const int wv   = (int)threadIdx.x >> 6;   // wave id 0..3 -> N-slice of 64 cols
    const int lr   = lane & 15;               // fragment row/col
    const int lk   = lane >> 4;               // k-group

    // ---- B fragments: W[l] (128x256 fp32, row-major [k][c]) -> registers ----
    // B layout for mfma_f32_16x16x32_bf16: col = lane&15, k = (lane>>4)*8 + j
    const float* Wl = W + (size_t)l * 128 * 256;
    bf16x8 bfrag[4][4];   // [kf][nf]
    #pragma unroll
    for (int kf = 0; kf < 4; ++kf) {
        const int k0 = kf*32 + lk*8;
        #pragma unroll
        for (int nf = 0; nf < 4; ++nf) {
            const int col = wv*64 + nf*16 + lr;
            bf16x8 t;
            #pragma unroll
            for (int j = 0; j < 8; ++j)
                t[j] = f2bf(Wl[(size_t)(k0 + j)*256 + col]);
            bfrag[kf][nf] = t;
        }
    }

    // ---- main loop over 16-row M-tiles ----
    for (int t = 0; t < ntiles; ++t) {
        const int m0 = row_start + t*16;

        // A fragment: row = lane&15, k = (lane>>4)*8 + j  (8 contiguous fp32)
        const float* arow = A + (size_t)(m0 + lr) * 128;
        bf16x8 af[4];
        #pragma unroll
        for (int kf = 0; kf < 4; ++kf) {
            const int k0 = kf*32 + lk*8;
            f32x4 x = *(const f32x4*)(arow + k0);
            f32x4 y = *(const f32x4*)(arow + k0 + 4);
            bf16x8 a;
            a[0]=f2bf(x[0]); a[1]=f2bf(x[1]); a[2]=f2bf(x[2]); a[3]=f2bf(x[3]);
            a[4]=f2bf(y[0]); a[5]=f2bf(y[1]); a[6]=f2bf(y[2]); a[7]=f2bf(y[3]);
            af[kf] = a;
        }

        f32x4 acc[4] = {{0.f,0.f,0.f,0.f},{0.f,0.f,0.f,0.f},
                        {0.f,0.f,0.f,0.f},{0.f,0.f,0.f,0.f}};
        #pragma unroll
        for (int kf = 0; kf < 4; ++kf)
            #pragma unroll
            for (int nf = 0; nf < 4; ++nf)
                acc[nf] = __builtin_amdgcn_mfma_f32_16x16x32_bf16(
                    af[kf], bfrag[kf][nf], acc[nf], 0, 0, 0);

        // C/D: col = lane&15, row = (lane>>4)*4 + reg
        float* orow = out + (outbase + (size_t)m0) * 256;
        #pragma unroll
        for (int nf = 0; nf < 4; ++nf) {
            const int c = wv*64 + nf*16 + lr;
            #pragma unroll
            for (int j = 0; j < 4; ++j) {
                const int r = lk*4 + j;
                orow[(size_t)r * 256 + c] = acc[nf][j];
            }
        }
    }
}

extern "C" void kernel_launch(void* const* d_in, const int* in_sizes, int n_in,
                              void* d_out, int out_size, void* d_ws, size_t ws_size,
                              hipStream_t stream) {
    (void)in_sizes; (void)n_in; (void)out_size; (void)d_ws; (void)ws_size;
    combine_mfma_kernel<<<dim3(2816), dim3(256), 0, stream>>>(
        (const float*)d_in[0], (const float*)d_in[1], (const float*)d_in[2],
        (const float*)d_in[3], (const float*)d_in[4], (const float*)d_in[5],
        (const float*)d_in[6], (float*)d_out);
}

// Round 5
// 366.215 us; speedup vs baseline: 1.0427x; 1.0427x over previous
//
#include <hip/hip_runtime.h>
#include <hip/hip_bf16.h>

typedef __attribute__((ext_vector_type(8))) short bf16x8;
typedef __attribute__((ext_vector_type(4))) float f32x4;

// fp32 -> bf16 RNE via HW-convertible cast (compiler fuses pairs to v_cvt_pk_bf16_f32)
__device__ __forceinline__ short f2bf(float f) {
    __hip_bfloat16 h = __float2bfloat16(f);
    return *reinterpret_cast<short*>(&h);
}

// Grid map (256 rows per block, rows_l = 20000*(2l+1), all multiples of 16):
// blocks per l: 79,235,391,547,704,860 ; cumulative: 0,79,314,705,1252,1956,2816
// 2816 = 11 * 256 CUs -> perfectly balanced.
__global__ void __launch_bounds__(256) combine_mfma_kernel(
    const float* __restrict__ A0, const float* __restrict__ A1,
    const float* __restrict__ A2, const float* __restrict__ A3,
    const float* __restrict__ A4, const float* __restrict__ A5,
    const float* __restrict__ W, float* __restrict__ out)
{
    int b = (int)blockIdx.x;
    int l, boff;
    if      (b <   79) { l = 0; boff = 0;    }
    else if (b <  314) { l = 1; boff = 79;   }
    else if (b <  705) { l = 2; boff = 314;  }
    else if (b < 1252) { l = 3; boff = 705;  }
    else if (b < 1956) { l = 4; boff = 1252; }
    else               { l = 5; boff = 1956; }
    const float* A = (l==0)?A0:(l==1)?A1:(l==2)?A2:(l==3)?A3:(l==4)?A4:A5;
    const int rows = 20000 * (2*l + 1);
    const int row_start = (b - boff) * 256;
    const int ntiles = min(256, rows - row_start) >> 4;   // 16-row MFMA tiles
    const size_t outbase = (size_t)20000 * l * l;         // sum of odd numbers = l^2

    const int lane = (int)threadIdx.x & 63;
    const int wv   = (int)threadIdx.x >> 6;   // wave id 0..3 -> N-slice of 64 cols
    const int lr   = lane & 15;
    const int lk   = lane >> 4;

    // ---- B fragments: W[l] (128x256 fp32, row-major [k][c]) -> registers ----
    // Used as the *A-operand* of the swapped MFMA: idx = lane&15 = col c,
    // k = (lane>>4)*8 + j  (identical lane structure to the B-operand layout).
    const float* Wl = W + (size_t)l * 128 * 256;
    bf16x8 bfrag[4][4];   // [kf][nf]
    #pragma unroll
    for (int kf = 0; kf < 4; ++kf) {
        const int k0 = kf*32 + lk*8;
        #pragma unroll
        for (int nf = 0; nf < 4; ++nf) {
            const int col = wv*64 + nf*16 + lr;
            bf16x8 t;
            #pragma unroll
            for (int j = 0; j < 8; ++j)
                t[j] = f2bf(Wl[(size_t)(k0 + j)*256 + col]);
            bfrag[kf][nf] = t;
        }
    }

    // ---- load+convert one 16-row A tile into MFMA B-operand fragments ----
    // B-operand layout: col = lane&15 = A-row (m0+lr), k = (lane>>4)*8 + j.
    auto load_tile = [&](int t, bf16x8* af) {
        const float* arow = A + (size_t)(row_start + t*16 + lr) * 128;
        #pragma unroll
        for (int kf = 0; kf < 4; ++kf) {
            const int k0 = kf*32 + lk*8;
            f32x4 x = *(const f32x4*)(arow + k0);
            f32x4 y = *(const f32x4*)(arow + k0 + 4);
            bf16x8 a;
            a[0]=f2bf(x[0]); a[1]=f2bf(x[1]); a[2]=f2bf(x[2]); a[3]=f2bf(x[3]);
            a[4]=f2bf(y[0]); a[5]=f2bf(y[1]); a[6]=f2bf(y[2]); a[7]=f2bf(y[3]);
            af[kf] = a;
        }
    };

    bf16x8 acur[4];
    load_tile(0, acur);

    for (int t = 0; t < ntiles; ++t) {
        // prefetch next tile (clamped -> branchless, always in-bounds)
        bf16x8 anext[4];
        load_tile(min(t + 1, ntiles - 1), anext);

        // Swapped MFMA: D = (W-slice as A-op) * (A-slice as B-op) = C^T tile.
        // Lane (lr,lk) ends up holding C[m0+lr][cb + lk*4 + reg], reg=0..3
        // -> 4 CONTIGUOUS output columns per acc register quad.
        f32x4 acc[4] = {{0.f,0.f,0.f,0.f},{0.f,0.f,0.f,0.f},
                        {0.f,0.f,0.f,0.f},{0.f,0.f,0.f,0.f}};
        #pragma unroll
        for (int kf = 0; kf < 4; ++kf)
            #pragma unroll
            for (int nf = 0; nf < 4; ++nf)
                acc[nf] = __builtin_amdgcn_mfma_f32_16x16x32_bf16(
                    bfrag[kf][nf], acur[kf], acc[nf], 0, 0, 0);

        // Coalesced epilogue: one dwordx4 per nf.
        const int m0 = row_start + t*16;
        float* orow = out + (outbase + (size_t)m0 + lr) * 256 + wv*64 + lk*4;
        #pragma unroll
        for (int nf = 0; nf < 4; ++nf)
            *(f32x4*)(orow + nf*16) = acc[nf];

        #pragma unroll
        for (int kf = 0; kf < 4; ++kf) acur[kf] = anext[kf];
    }
}

extern "C" void kernel_launch(void* const* d_in, const int* in_sizes, int n_in,
                              void* d_out, int out_size, void* d_ws, size_t ws_size,
                              hipStream_t stream) {
    (void)in_sizes; (void)n_in; (void)out_size; (void)d_ws; (void)ws_size;
    combine_mfma_kernel<<<dim3(2816), dim3(256), 0, stream>>>(
        (const float*)d_in[0], (const float*)d_in[1], (const float*)d_in[2],
        (const float*)d_in[3], (const float*)d_in[4], (const float*)d_in[5],
        (const float*)d_in[6], (float*)d_out);
}

// Round 7
// 231.877 us; speedup vs baseline: 1.6468x; 1.5793x over previous
//
#include <hip/hip_runtime.h>
#include <hip/hip_bf16.h>

typedef __attribute__((ext_vector_type(8))) short bf16x8;
typedef __attribute__((ext_vector_type(4))) float f32x4;

// fp32 -> bf16 RNE
__device__ __forceinline__ short f2bf(float f) {
    __hip_bfloat16 h = __float2bfloat16(f);
    return *reinterpret_cast<short*>(&h);
}

// Grid map (256 rows per block, rows_l = 20000*(2l+1), all multiples of 16):
// blocks per l: 79,235,391,547,704,860 ; cumulative: 0,79,314,705,1252,1956,2816
__global__ void __launch_bounds__(256) combine_mfma_kernel(
    const float* __restrict__ A0, const float* __restrict__ A1,
    const float* __restrict__ A2, const float* __restrict__ A3,
    const float* __restrict__ A4, const float* __restrict__ A5,
    const float* __restrict__ W, float* __restrict__ out)
{
    int b = (int)blockIdx.x;
    int l, boff;
    if      (b <   79) { l = 0; boff = 0;    }
    else if (b <  314) { l = 1; boff = 79;   }
    else if (b <  705) { l = 2; boff = 314;  }
    else if (b < 1252) { l = 3; boff = 705;  }
    else if (b < 1956) { l = 4; boff = 1252; }
    else               { l = 5; boff = 1956; }
    const float* A = (l==0)?A0:(l==1)?A1:(l==2)?A2:(l==3)?A3:(l==4)?A4:A5;
    const int rows = 20000 * (2*l + 1);
    const int row_start = (b - boff) * 256;
    const int ntiles = min(256, rows - row_start) >> 4;   // 16-row MFMA tiles
    const size_t outbase = (size_t)20000 * l * l;

    const int tid  = (int)threadIdx.x;
    const int lane = tid & 63;
    const int wv   = tid >> 6;    // wave id 0..3 -> 64-col N-slice
    const int lr   = lane & 15;
    const int lk   = lane >> 4;

    // Double-buffered A tile: 2 x (16 rows x 128 fp32) = 2 x 8 KB
    __shared__ float smem[4096];

    // ---- W fragments (used as swapped-MFMA A-operand), registers ----
    const float* Wl = W + (size_t)l * 128 * 256;
    bf16x8 bfrag[4][4];   // [kf][nf]
    #pragma unroll
    for (int kf = 0; kf < 4; ++kf) {
        const int k0 = kf*32 + lk*8;
        #pragma unroll
        for (int nf = 0; nf < 4; ++nf) {
            const int col = wv*64 + nf*16 + lr;
            bf16x8 t;
            #pragma unroll
            for (int j = 0; j < 8; ++j)
                t[j] = f2bf(Wl[(size_t)(k0 + j)*256 + col]);
            bfrag[kf][nf] = t;
        }
    }

    const char* Abase = (const char*)A + (size_t)row_start * 512;  // 512 B/row

    // Stage tile t into LDS buf via global_load_lds (linear LDS dest,
    // XOR-pre-swizzled GLOBAL source so ds_read can use the same XOR).
    // Swizzle: LDS byte L holds global byte L ^ (((L>>9)&7)<<4)  (within-row,
    // within-128B-chunk permutation -> line-level coalescing preserved).
    auto stage = [&](int t, int buf) {
        const char* tb = Abase + (size_t)t * 8192;
        #pragma unroll
        for (int j = 0; j < 2; ++j) {
            const int lin = wv*2048 + j*1024 + lane*16;       // LDS byte (linear)
            const int src = lin ^ (((lin >> 9) & 7) << 4);    // global byte
            __builtin_amdgcn_global_load_lds(
                (const __attribute__((address_space(1))) void*)(tb + src),
                (__attribute__((address_space(3))) void*)
                    ((char*)smem + buf*8192 + wv*2048 + j*1024),  // wave-uniform base
                16, 0, 0);
        }
    };

    // Fragment read: lane (lr,lk), kf wants A[lr][kf*32+lk*8 .. +8) =
    // global bytes G0 = lr*512 + kf*128 + lk*32 (two b128s). Read at G ^ swz.
    // Per-8-lane-round slot cover is complete -> conflict-free b128 reads.
    auto load_frags = [&](int buf, bf16x8* af) {
        const char* base = (const char*)smem + buf*8192;
        const int sw = (lr & 7) << 4;
        #pragma unroll
        for (int kf = 0; kf < 4; ++kf) {
            const int G0 = lr*512 + kf*128 + lk*32;
            f32x4 x = *(const f32x4*)(base + (G0 ^ sw));
            f32x4 y = *(const f32x4*)(base + ((G0 + 16) ^ sw));
            bf16x8 a;
            a[0]=f2bf(x[0]); a[1]=f2bf(x[1]); a[2]=f2bf(x[2]); a[3]=f2bf(x[3]);
            a[4]=f2bf(y[0]); a[5]=f2bf(y[1]); a[6]=f2bf(y[2]); a[7]=f2bf(y[3]);
            af[kf] = a;
        }
    };

    // Prologue: stage tile 0, full drain once (nothing else in flight).
    stage(0, 0);
    asm volatile("s_waitcnt vmcnt(0)" ::: "memory");
    __builtin_amdgcn_s_barrier();

    for (int t = 0; t < ntiles; ++t) {
        bf16x8 af[4];
        load_frags(t & 1, af);

        if (t + 1 < ntiles) stage(t + 1, (t + 1) & 1);  // issue early, no wait

        // Swapped MFMA: D = W-sliceT x A-sliceT -> lane holds C[m0+lr][cb+lk*4+reg]
        f32x4 acc[4] = {{0.f,0.f,0.f,0.f},{0.f,0.f,0.f,0.f},
                        {0.f,0.f,0.f,0.f},{0.f,0.f,0.f,0.f}};
        #pragma unroll
        for (int kf = 0; kf < 4; ++kf)
            #pragma unroll
            for (int nf = 0; nf < 4; ++nf)
                acc[nf] = __builtin_amdgcn_mfma_f32_16x16x32_bf16(
                    bfrag[kf][nf], af[kf], acc[nf], 0, 0, 0);

        // Coalesced epilogue: one dwordx4 per nf (fire and forget).
        const int m0 = row_start + t*16;
        float* orow = out + (outbase + (size_t)m0 + lr) * 256 + wv*64 + lk*4;
        #pragma unroll
        for (int nf = 0; nf < 4; ++nf)
            *(f32x4*)(orow + nf*16) = acc[nf];

        if (t + 1 < ntiles) {
            // Drain only stage(t+1) (the 2 oldest beyond the newest 4 stores);
            // this tile's 4 stores stay in flight across the barrier.
            asm volatile("s_waitcnt vmcnt(4)" ::: "memory");
            __builtin_amdgcn_s_barrier();
        }
    }
}

extern "C" void kernel_launch(void* const* d_in, const int* in_sizes, int n_in,
                              void* d_out, int out_size, void* d_ws, size_t ws_size,
                              hipStream_t stream) {
    (void)in_sizes; (void)n_in; (void)out_size; (void)d_ws; (void)ws_size;
    combine_mfma_kernel<<<dim3(2816), dim3(256), 0, stream>>>(
        (const float*)d_in[0], (const float*)d_in[1], (const float*)d_in[2],
        (const float*)d_in[3], (const float*)d_in[4], (const float*)d_in[5],
        (const float*)d_in[6], (float*)d_out);
}